// Round 10
// baseline (399.873 us; speedup 1.0000x reference)
//
#include <hip/hip_runtime.h>

// Problem constants (reference: BATCH=65536, SEQ_LEN=1024, M=32, DEGREE=7 -> D=8)
#define MM 32
#define DD 8
#define LL 1024
#define NBATCH 65536
#define NBLK 1024            // 64 rows per block, 4 blocks/CU, one generation
#define NPASS 32             // half-rows per wave

// Folded solve weights: Wt[i][d][j] = (Ginv_i * V_i^T)[d][j]. 32 KB, recomputed
// every launch (graph-capture safe), L2-resident for the main kernel.
__device__ float g_Wt[MM * DD * MM];

// ---------------------------------------------------------------------------
// Kernel 1: build Chebyshev Vandermonde per row-group i, form 8x8 Gram in
// fp64, Gauss-Jordan invert, fold: Wt[i][d][j] = sum_e Ginv[d][e] * V[j][e].
// ---------------------------------------------------------------------------
__global__ void precompute_w_kernel(const float* __restrict__ tg) {
    const int i = blockIdx.x;
    const int t = threadIdx.x;

    __shared__ float  V[MM][DD];        // V[j][e]
    __shared__ double A[DD][2 * DD];    // Gauss-Jordan augmented [G | I]

    if (t < MM) {
        float tt = tg[t * MM + i];      // times[i][j] = tg[j*32 + i]
        float c0 = 1.0f, c1 = tt;
        V[t][0] = c0;
        V[t][1] = c1;
        for (int e = 2; e < DD; ++e) {
            float c2 = 2.0f * tt * c1 - c0;
            V[t][e] = c2;
            c0 = c1; c1 = c2;
        }
    }
    __syncthreads();

    {
        int d = t >> 3, e = t & 7;
        double s = 0.0;
        for (int j = 0; j < MM; ++j) s += (double)V[j][d] * (double)V[j][e];
        A[d][e] = s;
        A[d][DD + e] = (d == e) ? 1.0 : 0.0;
    }
    __syncthreads();

    if (t == 0) {
        for (int p = 0; p < DD; ++p) {
            double inv = 1.0 / A[p][p];
            for (int c = p; c < 2 * DD; ++c) A[p][c] *= inv;
            for (int r2 = 0; r2 < DD; ++r2) {
                if (r2 == p) continue;
                double f = A[r2][p];
                for (int c = p; c < 2 * DD; ++c) A[r2][c] -= f * A[p][c];
            }
        }
    }
    __syncthreads();

    for (int k = t; k < DD * MM; k += 64) {
        int d = k >> 5;
        int j = k & 31;
        double s = 0.0;
        for (int e = 0; e < DD; ++e) s += A[d][DD + e] * (double)V[j][e];
        g_Wt[(i * DD + d) * MM + j] = (float)s;
    }
}

// ---------------------------------------------------------------------------
// Kernel 2: BARRIER-FREE. Each wave owns a private LDS slice and processes
// half-rows (16 i's) independently: producer == consumer == same wave, so
// correctness needs only per-wave lgkmcnt ordering — no __syncthreads, no
// block-wide vmcnt(0) drains. 16 independent waves/CU overlap stage/compute.
//  wave w: ihalf = w&1; rows rbase..rbase+31 with rbase = blk*64 + (w>>1)*32.
//  stage  (lane l): 8x global b32  x[row, ih*16 + (l&15) + 32*((l>>4)+4c)]
//                   (4x 64-B segments/instr; sibling wave consumes the other
//                   half-lines via L1/L2 — HBM still fetches each line once)
//                   -> 8x ds_write_b32 at (l&15)*36 + (l>>4) + 4c  (2-way, free)
//  compute (lane l -> iw=l>>2, dp=l&3): 8x ds_read_b128 of xTh[iw*36+4m]
//                   (4-lane broadcast + 2-way banks, free), 64 FMA with 64
//                   register weights, one coalesced float2 store.
// Ping-pong per wave; prefetch 2 passes ahead (same depth as round 9).
// ---------------------------------------------------------------------------
__global__ __launch_bounds__(256, 4) void poly_apply_kernel(
        const float* __restrict__ x,
        float* __restrict__ out) {
    __shared__ __align__(16) float xT[4][2][580];   // [wave][buf][16*36+4] = 18.6 KB

    const int t  = threadIdx.x;
    const int w  = t >> 6;          // wave 0..3
    const int l  = t & 63;          // lane
    const int ih = w & 1;           // i-half 0/1
    const int iw = l >> 2;          // i within half, 0..15
    const int dp = l & 3;           // d-pair 0..3

    const int rbase = blockIdx.x * 64 + (w >> 1) * 32;

    // Weights: w0[j]=Wt[ih*16+iw][2dp][j], w1[j]=Wt[..][2dp+1][j] (64 VGPRs,
    // one contiguous 256-B slab).
    float w0[32], w1[32];
    {
        const float4* wp = (const float4*)g_Wt + ((ih * 16 + iw) * DD + 2 * dp) * 8;
#pragma unroll
        for (int q = 0; q < 8; ++q) {
            float4 a = wp[q];
            w0[4 * q + 0] = a.x; w0[4 * q + 1] = a.y;
            w0[4 * q + 2] = a.z; w0[4 * q + 3] = a.w;
            float4 b = wp[q + 8];
            w1[4 * q + 0] = b.x; w1[4 * q + 1] = b.y;
            w1[4 * q + 2] = b.z; w1[4 * q + 3] = b.w;
        }
    }

    // Staging addresses.
    const int soff  = ih * 16 + (l & 15) + 32 * (l >> 4);   // global word offset in row
    const float* xp = x + (size_t)rbase * LL + soff;
    const int swoff = (l & 15) * 36 + (l >> 4);             // LDS word offset (j += 4c)

    float v[8];

    // Prologue: stage pass 0 into buf 0; prefetch pass 1 into regs.
#pragma unroll
    for (int c = 0; c < 8; ++c) v[c] = xp[128 * c];
#pragma unroll
    for (int c = 0; c < 8; ++c) xT[w][0][swoff + 4 * c] = v[c];
#pragma unroll
    for (int c = 0; c < 8; ++c) v[c] = xp[LL + 128 * c];

#pragma unroll 2
    for (int p = 0; p < NPASS; ++p) {
        // Write pass p+1 (in regs since one pass ago) into the other buffer.
        if (p + 1 < NPASS) {
#pragma unroll
            for (int c = 0; c < 8; ++c) xT[w][(p + 1) & 1][swoff + 4 * c] = v[c];
        }
        // Prefetch pass p+2.
        if (p + 2 < NPASS) {
#pragma unroll
            for (int c = 0; c < 8; ++c) v[c] = xp[(size_t)(p + 2) * LL + 128 * c];
        }

        // Compute half-row (rbase+p, ihalf) from buf[p&1].
        {
            const float* xb = &xT[w][p & 1][iw * 36];
            float a0 = 0.f, a1 = 0.f;
#pragma unroll
            for (int m = 0; m < 8; ++m) {
                float4 xq = *(const float4*)&xb[4 * m];
                a0 = fmaf(w0[4 * m + 0], xq.x, a0);
                a1 = fmaf(w1[4 * m + 0], xq.x, a1);
                a0 = fmaf(w0[4 * m + 1], xq.y, a0);
                a1 = fmaf(w1[4 * m + 1], xq.y, a1);
                a0 = fmaf(w0[4 * m + 2], xq.z, a0);
                a1 = fmaf(w1[4 * m + 2], xq.z, a1);
                a0 = fmaf(w0[4 * m + 3], xq.w, a0);
                a1 = fmaf(w1[4 * m + 3], xq.w, a1);
            }
            float2 o; o.x = a0; o.y = a1;
            *(float2*)&out[(size_t)(rbase + p) * 256 + (ih * 16 + iw) * 8 + 2 * dp] = o;
        }
        // NO barrier: per-wave lgkmcnt ordering is sufficient (private slice).
    }
}

extern "C" void kernel_launch(void* const* d_in, const int* in_sizes, int n_in,
                              void* d_out, int out_size, void* d_ws, size_t ws_size,
                              hipStream_t stream) {
    const float* x  = (const float*)d_in[0];   // [65536, 1024] f32
    const float* tg = (const float*)d_in[1];   // [1024] f32
    float* out = (float*)d_out;                // [65536, 32, 8] f32
    (void)d_ws; (void)ws_size;

    precompute_w_kernel<<<32, 64, 0, stream>>>(tg);
    poly_apply_kernel<<<NBLK, 256, 0, stream>>>(x, out);
}